// Round 1
// baseline (389.305 us; speedup 1.0000x reference)
//
#include <hip/hip_runtime.h>

// Problem constants (fixed by reference):
//   x: [8192, 4096] fp32,  q: [4096, 4096] int32 (codes 0..126),
//   scale: [1] fp32,  out = x @ (q*scale)^T : [8192, 4096] fp32
// Strategy: convert x->bf16 and q->bf16 in workspace, then bf16 MFMA GEMM
// (m97 structure: 128x128 tile, BK=32, global_load_lds width 16), scale in
// the fp32 epilogue.

typedef unsigned short ushort_t;
typedef __attribute__((ext_vector_type(8))) __bf16 bf16x8;
typedef __attribute__((ext_vector_type(8))) unsigned short ushort8;
typedef __attribute__((ext_vector_type(4))) float f32x4;
typedef __attribute__((ext_vector_type(4))) float float4v;
typedef __attribute__((ext_vector_type(4))) int int4v;

constexpr int Mdim = 8192;
constexpr int Ndim = 4096;
constexpr int Kdim = 4096;
constexpr int BM = 128, BN = 128, BK = 32;
constexpr int NT_N = Ndim / BN;              // 32 tiles in N
constexpr int NWG = (Mdim / BM) * (Ndim / BN); // 2048 blocks

#define GLOAD_LDS16(gp, lp)                                                  \
  __builtin_amdgcn_global_load_lds(                                          \
      (const __attribute__((address_space(1))) void*)(gp),                   \
      (__attribute__((address_space(3))) void*)(lp), 16, 0, 0)

// ---- float -> bf16 (RNE), exact for small ints -----------------------------
__device__ inline unsigned short f2bf(float f) {
  unsigned u = __builtin_bit_cast(unsigned, f);
  unsigned r = u + 0x7FFFu + ((u >> 16) & 1u);
  return (unsigned short)(r >> 16);
}

// ---- conversion kernels ----------------------------------------------------
__global__ void cvt_f32_bf16(const float* __restrict__ in,
                             ushort_t* __restrict__ out, int n8) {
  int i = blockIdx.x * blockDim.x + threadIdx.x;
  const int stride = gridDim.x * blockDim.x;
  for (; i < n8; i += stride) {
    const float4v* p = (const float4v*)(in + (size_t)i * 8);
    float4v v0 = p[0], v1 = p[1];
    ushort8 o;
    o[0] = f2bf(v0[0]); o[1] = f2bf(v0[1]); o[2] = f2bf(v0[2]); o[3] = f2bf(v0[3]);
    o[4] = f2bf(v1[0]); o[5] = f2bf(v1[1]); o[6] = f2bf(v1[2]); o[7] = f2bf(v1[3]);
    *(ushort8*)(out + (size_t)i * 8) = o;
  }
}

__global__ void cvt_i32_bf16(const int* __restrict__ in,
                             ushort_t* __restrict__ out, int n8) {
  int i = blockIdx.x * blockDim.x + threadIdx.x;
  const int stride = gridDim.x * blockDim.x;
  for (; i < n8; i += stride) {
    const int4v* p = (const int4v*)(in + (size_t)i * 8);
    int4v v0 = p[0], v1 = p[1];
    ushort8 o;
    o[0] = f2bf((float)v0[0]); o[1] = f2bf((float)v0[1]);
    o[2] = f2bf((float)v0[2]); o[3] = f2bf((float)v0[3]);
    o[4] = f2bf((float)v1[0]); o[5] = f2bf((float)v1[1]);
    o[6] = f2bf((float)v1[2]); o[7] = f2bf((float)v1[3]);
    *(ushort8*)(out + (size_t)i * 8) = o;
  }
}

// ---- bf16 GEMM: C = A * B^T, A[M][K], B[N][K] (both bf16), C fp32 ----------
// m97 structure: 128x128 tile, BK=32, 4 waves each owning a 64x64 subtile
// as 4x4 fragments of 16x16; staging via global_load_lds width=16.
__global__ __launch_bounds__(256, 2) void gemm_bt_bf16(
    const ushort_t* __restrict__ A, const ushort_t* __restrict__ B,
    float* __restrict__ C, const float* __restrict__ scale_p) {
  __shared__ ushort_t sA[BM * BK];  // [128][32] bf16, 8 KB
  __shared__ ushort_t sB[BN * BK];  // 8 KB

  const int tid = threadIdx.x;
  const int wid = tid >> 6;
  const int lane = tid & 63;

  // XCD-aware swizzle (NWG % 8 == 0 -> simple form is bijective)
  const int bid = blockIdx.x;
  const int swz = (bid & 7) * (NWG / 8) + (bid >> 3);
  const int mt = swz / NT_N;
  const int nt = swz % NT_N;
  const int brow = mt * BM;
  const int bcol = nt * BN;

  const int wr = wid >> 1;  // wave row 0..1
  const int wc = wid & 1;   // wave col 0..1

  f32x4 acc[4][4] = {};

  // Staging geometry: tile is row-major [128][BK]; thread t covers 8 bf16
  // at linear element e = s*2048 + t*8 (s = half 0/1): r = e>>5, c = e&31.
  const int e0 = tid * 8;
  const int r0 = e0 >> 5;
  const int c0 = e0 & 31;
  const ushort_t* pa0 = A + (size_t)(brow + r0) * Kdim + c0;
  const ushort_t* pa1 = A + (size_t)(brow + r0 + 64) * Kdim + c0;
  const ushort_t* pb0 = B + (size_t)(bcol + r0) * Kdim + c0;
  const ushort_t* pb1 = B + (size_t)(bcol + r0 + 64) * Kdim + c0;

  // wave-uniform LDS bases (elements): half s at s*2048 + wid*512
  ushort_t* lA0 = sA + wid * 512;
  ushort_t* lA1 = sA + 2048 + wid * 512;
  ushort_t* lB0 = sB + wid * 512;
  ushort_t* lB1 = sB + 2048 + wid * 512;

  // fragment read offsets (elements)
  const int fr = lane & 15;
  const int ko = (lane >> 4) * 8;
  const int aoff = (wr * 64 + fr) * BK + ko;
  const int boff = (wc * 64 + fr) * BK + ko;

  const int kSteps = Kdim / BK;  // 128
  for (int kt = 0; kt < kSteps; ++kt) {
    GLOAD_LDS16(pa0, lA0);
    GLOAD_LDS16(pa1, lA1);
    GLOAD_LDS16(pb0, lB0);
    GLOAD_LDS16(pb1, lB1);
    pa0 += BK; pa1 += BK; pb0 += BK; pb1 += BK;
    __syncthreads();  // drains vmcnt -> staged tile visible

    bf16x8 af[4];
    bf16x8 bfr[4];
#pragma unroll
    for (int mr = 0; mr < 4; ++mr)
      af[mr] = *(const bf16x8*)(const void*)(sA + aoff + mr * 16 * BK);
#pragma unroll
    for (int nr = 0; nr < 4; ++nr)
      bfr[nr] = *(const bf16x8*)(const void*)(sB + boff + nr * 16 * BK);

#pragma unroll
    for (int mr = 0; mr < 4; ++mr)
#pragma unroll
      for (int nr = 0; nr < 4; ++nr)
        acc[mr][nr] = __builtin_amdgcn_mfma_f32_16x16x32_bf16(
            af[mr], bfr[nr], acc[mr][nr], 0, 0, 0);
    __syncthreads();  // all waves done reading before next stage
  }

  // Epilogue: D layout col=lane&15, row=(lane>>4)*4+j  [verified m89/m91]
  const float s = *scale_p;
  const int orow = brow + wr * 64;
  const int ocol = bcol + wc * 64 + (lane & 15);
  const int rbase = (lane >> 4) * 4;
#pragma unroll
  for (int mr = 0; mr < 4; ++mr)
#pragma unroll
    for (int nr = 0; nr < 4; ++nr)
#pragma unroll
      for (int j = 0; j < 4; ++j)
        C[(size_t)(orow + mr * 16 + rbase + j) * Ndim + (ocol + nr * 16)] =
            acc[mr][nr][j] * s;
}

extern "C" void kernel_launch(void* const* d_in, const int* in_sizes, int n_in,
                              void* d_out, int out_size, void* d_ws,
                              size_t ws_size, hipStream_t stream) {
  const float* x = (const float*)d_in[0];
  const int* q = (const int*)d_in[1];
  const float* scale = (const float*)d_in[2];
  float* out = (float*)d_out;

  const size_t xbf_elems = (size_t)Mdim * Kdim;  // 33.5M bf16 = 67 MB
  const size_t qbf_elems = (size_t)Ndim * Kdim;  // 16.8M bf16 = 33.5 MB
  const size_t ws_needed = (xbf_elems + qbf_elems) * sizeof(ushort_t);
  if (ws_size < ws_needed) return;  // loud failure -> signals ws too small

  ushort_t* xbf = (ushort_t*)d_ws;
  ushort_t* qbf = xbf + xbf_elems;

  cvt_f32_bf16<<<2048, 256, 0, stream>>>(x, xbf, (int)(xbf_elems / 8));
  cvt_i32_bf16<<<2048, 256, 0, stream>>>(q, qbf, (int)(qbf_elems / 8));
  gemm_bt_bf16<<<NWG, 256, 0, stream>>>(xbf, qbf, out, scale);
}

// Round 2
// 297.876 us; speedup vs baseline: 1.3069x; 1.3069x over previous
//
#include <hip/hip_runtime.h>

// out[8192,4096] = x[8192,4096] @ (q[4096,4096]*scale)^T
// Stage 1: convert x->bf16, q->bf16 into d_ws.
// Stage 2: 256x256-tile bf16 MFMA GEMM, BK=64, 8 waves (2Mx4N), deep-pipelined
//   4-phase-per-K-tile schedule: counted vmcnt(4) (never 0 in main loop),
//   XOR-swizzled LDS (pre-swizzled global source + swizzled ds_read),
//   setprio(1) around each 16-MFMA cluster.

typedef unsigned short u16;
typedef __attribute__((ext_vector_type(8))) __bf16 bf16x8;
typedef __attribute__((ext_vector_type(8))) unsigned short ushort8;
typedef __attribute__((ext_vector_type(4))) float f32x4;
typedef __attribute__((ext_vector_type(4))) float float4v;
typedef __attribute__((ext_vector_type(4))) int int4v;

constexpr int Mdim = 8192, Ndim = 4096, Kdim = 4096;
constexpr int BM = 256, BN = 256, BK = 64;
constexpr int NT_N = Ndim / BN;                 // 16
constexpr int NWG = (Mdim / BM) * (Ndim / BN);  // 32*16 = 512 (%8==0 -> simple XCD swizzle bijective)
constexpr int NTILES = Kdim / BK;               // 64

#define GLOAD16(gp, lp)                                                      \
  __builtin_amdgcn_global_load_lds(                                          \
      (const __attribute__((address_space(1))) void*)(gp),                   \
      (__attribute__((address_space(3))) void*)(lp), 16, 0, 0)
#define FENCE() asm volatile("" ::: "memory")
#define BARRIER()                      \
  do {                                 \
    FENCE();                           \
    __builtin_amdgcn_s_barrier();      \
    FENCE();                           \
  } while (0)

// ---- float -> bf16 (RNE) ---------------------------------------------------
__device__ inline unsigned short f2bf(float f) {
  unsigned u = __builtin_bit_cast(unsigned, f);
  unsigned r = u + 0x7FFFu + ((u >> 16) & 1u);
  return (unsigned short)(r >> 16);
}

__global__ void cvt_f32_bf16(const float* __restrict__ in,
                             u16* __restrict__ out, int n8) {
  int i = blockIdx.x * blockDim.x + threadIdx.x;
  const int stride = gridDim.x * blockDim.x;
  for (; i < n8; i += stride) {
    const float4v* p = (const float4v*)(in + (size_t)i * 8);
    float4v v0 = p[0], v1 = p[1];
    ushort8 o;
    o[0] = f2bf(v0[0]); o[1] = f2bf(v0[1]); o[2] = f2bf(v0[2]); o[3] = f2bf(v0[3]);
    o[4] = f2bf(v1[0]); o[5] = f2bf(v1[1]); o[6] = f2bf(v1[2]); o[7] = f2bf(v1[3]);
    *(ushort8*)(out + (size_t)i * 8) = o;
  }
}

__global__ void cvt_i32_bf16(const int* __restrict__ in,
                             u16* __restrict__ out, int n8) {
  int i = blockIdx.x * blockDim.x + threadIdx.x;
  const int stride = gridDim.x * blockDim.x;
  for (; i < n8; i += stride) {
    const int4v* p = (const int4v*)(in + (size_t)i * 8);
    int4v v0 = p[0], v1 = p[1];
    ushort8 o;
    o[0] = f2bf((float)v0[0]); o[1] = f2bf((float)v0[1]);
    o[2] = f2bf((float)v0[2]); o[3] = f2bf((float)v0[3]);
    o[4] = f2bf((float)v1[0]); o[5] = f2bf((float)v1[1]);
    o[6] = f2bf((float)v1[2]); o[7] = f2bf((float)v1[3]);
    *(ushort8*)(out + (size_t)i * 8) = o;
  }
}

// ---- 256x256 deep-pipelined bf16 GEMM: C = A * B^T -------------------------
// LDS: sX[dbuf][khalf][256*32] bf16 (16 KB per half). 128 KiB total.
// Swizzle (element-index): e ^= ((e>>6)&3)<<3  -> 2-way banks on ds_read_b128
// (free, m136). Applied on ds_read addr; inverse (same involution) applied to
// the per-lane GLOBAL source column so global_load_lds dest stays linear.
//
// Schedule per K-tile u (buf = u&1), phases = (C-half ch, K-half kh):
//  ph1 (ch0,kh0): ld B0,A | stage (u+1) A-kh1 -> buf^1 | bar | 16 mfma | bar
//  ph2 (ch1,kh0): ld A    | stage (u+1) B-kh1 -> buf^1 | bar | 16 mfma | bar
//  ph3 (ch0,kh1): ld B1,A | stage (u+2) A-kh0 -> buf   | bar | 16 mfma | bar
//  ph4 (ch1,kh1): ld A    | stage (u+2) B-kh0 -> buf   | bar | 16 mfma |
//                 vmcnt(4) | bar
// Every stage's LDS slot had its last ds_read >=1 barrier earlier; the
// per-tile vmcnt(4) leaves exactly 2 half-tiles (4 loads/wave) in flight.
__global__ __launch_bounds__(512, 2) void gemm_bt_256(
    const u16* __restrict__ A, const u16* __restrict__ B,
    float* __restrict__ C, const float* __restrict__ scale_p) {
  __shared__ u16 sA[2][2][BM * 32];  // 64 KB
  __shared__ u16 sB[2][2][BN * 32];  // 64 KB

  const int tid = threadIdx.x;
  const int wid = tid >> 6, lane = tid & 63;
  const int fr = lane & 15;
  // swizzled k-offset for fragment reads (row ≡ fr mod 16, bases mult of 16)
  const int ko = ((lane >> 4) * 8) ^ (((fr >> 1) & 3) << 3);

  const int bid = blockIdx.x;
  const int swz = (bid & 7) * (NWG / 8) + (bid >> 3);
  const int mt = swz / NT_N, ntl = swz % NT_N;
  const int brow = mt * BM, bcol = ntl * BN;

  const int wm = wid >> 2, wn = wid & 3;  // 2 x 4 wave grid

  // Per-thread staging source geometry (fixed): issue j covers LDS elements
  // [j*4096 + wid*512 + lane*8, +8). Source col is swizzle-permuted.
  const u16* srcA[2];
  const u16* srcB[2];
#pragma unroll
  for (int j = 0; j < 2; ++j) {
    const int p = j * 4096 + wid * 512 + lane * 8;
    const int r = p >> 5;
    const int c = (p & 31) ^ (((p >> 6) & 3) << 3);
    srcA[j] = A + (size_t)(brow + r) * Kdim + c;
    srcB[j] = B + (size_t)(bcol + r) * Kdim + c;
  }

  auto stageA = [&](int b, int kh, int t) {
#pragma unroll
    for (int j = 0; j < 2; ++j)
      GLOAD16(srcA[j] + t * BK + kh * 32, &sA[b][kh][j * 4096 + wid * 512]);
  };
  auto stageB = [&](int b, int kh, int t) {
#pragma unroll
    for (int j = 0; j < 2; ++j)
      GLOAD16(srcB[j] + t * BK + kh * 32, &sB[b][kh][j * 4096 + wid * 512]);
  };
  auto loadA = [&](bf16x8* af, int b, int kh, int ch) {
#pragma unroll
    for (int m = 0; m < 4; ++m)
      af[m] = *(const bf16x8*)(const void*)&sA[b][kh]
                  [(wm * 128 + ch * 64 + m * 16 + fr) * 32 + ko];
  };
  auto loadB = [&](bf16x8* bf, int b, int kh) {
#pragma unroll
    for (int n = 0; n < 4; ++n)
      bf[n] = *(const bf16x8*)(const void*)&sB[b][kh]
                  [(wn * 64 + n * 16 + fr) * 32 + ko];
  };

  f32x4 acc[8][4] = {};  // [ch*4 + m][n]

  auto mma16 = [&](f32x4(*accp)[4], const bf16x8* af, const bf16x8* bf) {
    __builtin_amdgcn_s_setprio(1);
#pragma unroll
    for (int m = 0; m < 4; ++m)
#pragma unroll
      for (int n = 0; n < 4; ++n)
        accp[m][n] = __builtin_amdgcn_mfma_f32_16x16x32_bf16(
            af[m], bf[n], accp[m][n], 0, 0, 0);
    __builtin_amdgcn_s_setprio(0);
  };

  // Prologue: tile0 complete + tile1's kh0 halves in flight.
  stageA(0, 0, 0); stageB(0, 0, 0);
  stageA(0, 1, 0); stageB(0, 1, 0);
  stageA(1, 0, 1); stageB(1, 0, 1);
  asm volatile("s_waitcnt vmcnt(4)" ::: "memory");  // tile0 landed
  BARRIER();

#pragma unroll 2
  for (int u = 0; u < NTILES; ++u) {
    const int buf = u & 1;
    bf16x8 a[4], b0[4], b1[4];

    // ph1: (ch0, kh0)
    loadB(b0, buf, 0);
    loadA(a, buf, 0, 0);
    if (u + 1 < NTILES) stageA(buf ^ 1, 1, u + 1);
    BARRIER();
    mma16(&acc[0], a, b0);
    BARRIER();

    // ph2: (ch1, kh0)
    loadA(a, buf, 0, 1);
    if (u + 1 < NTILES) stageB(buf ^ 1, 1, u + 1);
    BARRIER();
    mma16(&acc[4], a, b0);
    BARRIER();

    // ph3: (ch0, kh1)
    loadB(b1, buf, 1);
    loadA(a, buf, 1, 0);
    if (u + 2 < NTILES) stageA(buf, 0, u + 2);
    BARRIER();
    mma16(&acc[0], a, b1);
    BARRIER();

    // ph4: (ch1, kh1)
    loadA(a, buf, 1, 1);
    if (u + 2 < NTILES) stageB(buf, 0, u + 2);
    BARRIER();
    mma16(&acc[4], a, b1);
    if (u < NTILES - 2) {
      asm volatile("s_waitcnt vmcnt(4)" ::: "memory");  // next tile landed
    } else {
      asm volatile("s_waitcnt vmcnt(0)" ::: "memory");  // epilogue drain
    }
    BARRIER();
  }

  // Epilogue: D layout col=lane&15, row=(lane>>4)*4+j (m89/m91-verified)
  const float s = *scale_p;
  const int col0 = bcol + wn * 64 + fr;
  const int row0 = brow + wm * 128 + (lane >> 4) * 4;
#pragma unroll
  for (int ch = 0; ch < 2; ++ch)
#pragma unroll
    for (int m = 0; m < 4; ++m)
#pragma unroll
      for (int n = 0; n < 4; ++n)
#pragma unroll
        for (int j = 0; j < 4; ++j)
          C[(size_t)(row0 + ch * 64 + m * 16 + j) * Ndim + (col0 + n * 16)] =
              acc[ch * 4 + m][n][j] * s;
}

extern "C" void kernel_launch(void* const* d_in, const int* in_sizes, int n_in,
                              void* d_out, int out_size, void* d_ws,
                              size_t ws_size, hipStream_t stream) {
  const float* x = (const float*)d_in[0];
  const int* q = (const int*)d_in[1];
  const float* scale = (const float*)d_in[2];
  float* out = (float*)d_out;

  const size_t xbf_elems = (size_t)Mdim * Kdim;
  const size_t qbf_elems = (size_t)Ndim * Kdim;
  const size_t ws_needed = (xbf_elems + qbf_elems) * sizeof(u16);
  if (ws_size < ws_needed) return;

  u16* xbf = (u16*)d_ws;
  u16* qbf = xbf + xbf_elems;

  cvt_f32_bf16<<<2048, 256, 0, stream>>>(x, xbf, (int)(xbf_elems / 8));
  cvt_i32_bf16<<<2048, 256, 0, stream>>>(q, qbf, (int)(qbf_elems / 8));
  gemm_bt_256<<<NWG, 512, 0, stream>>>(xbf, qbf, out, scale);
}

// Round 3
// 294.582 us; speedup vs baseline: 1.3216x; 1.0112x over previous
//
#include <hip/hip_runtime.h>

// out[8192,4096] = x[8192,4096] @ (q[4096,4096]*scale)^T
// Stage 1: convert x->bf16, q->bf16 into d_ws.
// Stage 2: 256x256-tile bf16 MFMA GEMM, BK=64, 8 waves (2Mx4N):
//   - 4 phases per K-tile, 2 barriers per phase (m201-style lockstep)
//   - deep pipeline: TWO s_waitcnt vmcnt(8) per tile (mid + end), never 0 in
//     the main loop; 12 loads max in flight; issue->wait ~4 phases
//   - T2 XOR-swizzled LDS (pre-swizzled global source + swizzled ds_read)
//   - T5 setprio around each 16-MFMA cluster; XCD-swizzled blockIdx

typedef unsigned short u16;
typedef __attribute__((ext_vector_type(8))) __bf16 bf16x8;
typedef __attribute__((ext_vector_type(8))) unsigned short ushort8;
typedef __attribute__((ext_vector_type(4))) float f32x4;
typedef __attribute__((ext_vector_type(4))) float float4v;
typedef __attribute__((ext_vector_type(4))) int int4v;

constexpr int Mdim = 8192, Ndim = 4096, Kdim = 4096;
constexpr int BM = 256, BN = 256, BK = 64;
constexpr int NT_N = Ndim / BN;                 // 16
constexpr int NWG = (Mdim / BM) * (Ndim / BN);  // 512 (%8==0 -> simple XCD swizzle bijective)
constexpr int NTILES = Kdim / BK;               // 64

#define GLOAD16(gp, lp)                                                      \
  __builtin_amdgcn_global_load_lds(                                          \
      (const __attribute__((address_space(1))) void*)(gp),                   \
      (__attribute__((address_space(3))) void*)(lp), 16, 0, 0)
#define FENCE() asm volatile("" ::: "memory")
#define BARRIER()                      \
  do {                                 \
    FENCE();                           \
    __builtin_amdgcn_s_barrier();      \
    FENCE();                           \
  } while (0)
#define WAIT_VM(n) asm volatile("s_waitcnt vmcnt(" #n ")" ::: "memory")

// ---- float -> bf16 (RNE) ---------------------------------------------------
__device__ inline unsigned short f2bf(float f) {
  unsigned u = __builtin_bit_cast(unsigned, f);
  unsigned r = u + 0x7FFFu + ((u >> 16) & 1u);
  return (unsigned short)(r >> 16);
}

__global__ void cvt_f32_bf16(const float* __restrict__ in,
                             u16* __restrict__ out, int n8) {
  int i = blockIdx.x * blockDim.x + threadIdx.x;
  const int stride = gridDim.x * blockDim.x;
  for (; i < n8; i += stride) {
    const float4v* p = (const float4v*)(in + (size_t)i * 8);
    float4v v0 = p[0], v1 = p[1];
    ushort8 o;
    o[0] = f2bf(v0[0]); o[1] = f2bf(v0[1]); o[2] = f2bf(v0[2]); o[3] = f2bf(v0[3]);
    o[4] = f2bf(v1[0]); o[5] = f2bf(v1[1]); o[6] = f2bf(v1[2]); o[7] = f2bf(v1[3]);
    *(ushort8*)(out + (size_t)i * 8) = o;
  }
}

__global__ void cvt_i32_bf16(const int* __restrict__ in,
                             u16* __restrict__ out, int n8) {
  int i = blockIdx.x * blockDim.x + threadIdx.x;
  const int stride = gridDim.x * blockDim.x;
  for (; i < n8; i += stride) {
    const int4v* p = (const int4v*)(in + (size_t)i * 8);
    int4v v0 = p[0], v1 = p[1];
    ushort8 o;
    o[0] = f2bf((float)v0[0]); o[1] = f2bf((float)v0[1]);
    o[2] = f2bf((float)v0[2]); o[3] = f2bf((float)v0[3]);
    o[4] = f2bf((float)v1[0]); o[5] = f2bf((float)v1[1]);
    o[6] = f2bf((float)v1[2]); o[7] = f2bf((float)v1[3]);
    *(ushort8*)(out + (size_t)i * 8) = o;
  }
}

// ---- 256x256 deep-pipelined bf16 GEMM: C = A * B^T -------------------------
// LDS: sX[dbuf][khalf][256*32] bf16 (16 KB per half). 128 KiB total.
// Swizzle (element-index): e ^= ((e>>6)&3)<<3 -> at most 2-way banks on
// ds_read_b128 (free, m136). Same involution on ds_read addr and on the
// per-lane GLOBAL source column (global_load_lds dest stays linear, m104).
//
// Stages issued during tile u: S1=A(u+1,kh1) S2=B(u+1,kh1) S3=A(u+2,kh0)
// S4=B(u+2,kh0), 2 loads each, per wave. Deadlines:
//   (u,kh0) read at ph1/ph2 of u  <- staged S3/S4(u-2)
//   (u,kh1) read at ph3/ph4 of u  <- staged S1/S2(u-1)
// Waits (each immediately before the barrier that precedes the consuming
// ds_reads, so per-wave vmcnt covers all waves):
//   mid-tile  (end ph2): vmcnt(8) -> forces S1,S2(u-1)   [kh1 of tile u]
//   end-tile  (end ph4): vmcnt(8) -> forces S3,S4(u-1)   [kh0 of tile u+1]
__global__ __launch_bounds__(512, 2) void gemm_bt_256(
    const u16* __restrict__ A, const u16* __restrict__ B,
    float* __restrict__ C, const float* __restrict__ scale_p) {
  __shared__ u16 sA[2][2][BM * 32];  // 64 KB
  __shared__ u16 sB[2][2][BN * 32];  // 64 KB

  const int tid = threadIdx.x;
  const int wid = tid >> 6, lane = tid & 63;
  const int fr = lane & 15;
  const int ko = ((lane >> 4) * 8) ^ (((fr >> 1) & 3) << 3);

  const int bid = blockIdx.x;
  const int swz = (bid & 7) * (NWG / 8) + (bid >> 3);
  const int mt = swz / NT_N, ntl = swz % NT_N;
  const int brow = mt * BM, bcol = ntl * BN;

  const int wm = wid >> 2, wn = wid & 3;  // 2 x 4 wave grid

  const u16* srcA[2];
  const u16* srcB[2];
#pragma unroll
  for (int j = 0; j < 2; ++j) {
    const int p = j * 4096 + wid * 512 + lane * 8;
    const int r = p >> 5;
    const int c = (p & 31) ^ (((p >> 6) & 3) << 3);
    srcA[j] = A + (size_t)(brow + r) * Kdim + c;
    srcB[j] = B + (size_t)(bcol + r) * Kdim + c;
  }

  auto stageA = [&](int b, int kh, int t) {
#pragma unroll
    for (int j = 0; j < 2; ++j)
      GLOAD16(srcA[j] + t * BK + kh * 32, &sA[b][kh][j * 4096 + wid * 512]);
  };
  auto stageB = [&](int b, int kh, int t) {
#pragma unroll
    for (int j = 0; j < 2; ++j)
      GLOAD16(srcB[j] + t * BK + kh * 32, &sB[b][kh][j * 4096 + wid * 512]);
  };
  auto loadA = [&](bf16x8* af, int b, int kh, int ch) {
#pragma unroll
    for (int m = 0; m < 4; ++m)
      af[m] = *(const bf16x8*)(const void*)&sA[b][kh]
                  [(wm * 128 + ch * 64 + m * 16 + fr) * 32 + ko];
  };
  auto loadB = [&](bf16x8* bf, int b, int kh) {
#pragma unroll
    for (int n = 0; n < 4; ++n)
      bf[n] = *(const bf16x8*)(const void*)&sB[b][kh]
                  [(wn * 64 + n * 16 + fr) * 32 + ko];
  };

  f32x4 acc[8][4] = {};  // [ch*4 + m][n]

  auto mma16 = [&](f32x4(*accp)[4], const bf16x8* af, const bf16x8* bf) {
    __builtin_amdgcn_s_setprio(1);
#pragma unroll
    for (int m = 0; m < 4; ++m)
#pragma unroll
      for (int n = 0; n < 4; ++n)
        accp[m][n] = __builtin_amdgcn_mfma_f32_16x16x32_bf16(
            af[m], bf[n], accp[m][n], 0, 0, 0);
    __builtin_amdgcn_s_setprio(0);
  };

  // Prologue: tile0 complete (8 loads) + tile1-kh0 (4 loads) in flight.
  stageA(0, 0, 0); stageB(0, 0, 0);
  stageA(0, 1, 0); stageB(0, 1, 0);
  stageA(1, 0, 1); stageB(1, 0, 1);
  WAIT_VM(4);  // tile0 landed; tile1-kh0 may still fly
  BARRIER();

#pragma unroll 2
  for (int u = 0; u < NTILES; ++u) {
    const int buf = u & 1;
    const int t1 = (u + 1 < NTILES) ? u + 1 : NTILES - 1;  // clamped (WAR-safe)
    const int t2 = (u + 2 < NTILES) ? u + 2 : NTILES - 1;
    bf16x8 a[4], b0[4], b1[4];

    // ph1: (ch0, kh0)
    loadB(b0, buf, 0);
    loadA(a, buf, 0, 0);
    stageA(buf ^ 1, 1, t1);  // S1
    BARRIER();
    mma16(&acc[0], a, b0);
    BARRIER();

    // ph2: (ch1, kh0)
    loadA(a, buf, 0, 1);
    stageB(buf ^ 1, 1, t1);  // S2
    BARRIER();
    mma16(&acc[4], a, b0);
    WAIT_VM(8);  // forces S1,S2(u-1): this tile's kh1 landed (read in ph3)
    BARRIER();

    // ph3: (ch0, kh1)
    loadB(b1, buf, 1);
    loadA(a, buf, 1, 0);
    stageA(buf, 0, t2);  // S3
    BARRIER();
    mma16(&acc[0], a, b1);
    BARRIER();

    // ph4: (ch1, kh1)
    loadA(a, buf, 1, 1);
    stageB(buf, 0, t2);  // S4
    BARRIER();
    mma16(&acc[4], a, b1);
    WAIT_VM(8);  // forces S3,S4(u-1): next tile's kh0 landed (read in ph1)
    BARRIER();
  }

  // Epilogue: D layout col=lane&15, row=(lane>>4)*4+j (m89/m91-verified)
  const float s = *scale_p;
  const int col0 = bcol + wn * 64 + fr;
  const int row0 = brow + wm * 128 + (lane >> 4) * 4;
#pragma unroll
  for (int ch = 0; ch < 2; ++ch)
#pragma unroll
    for (int m = 0; m < 4; ++m)
#pragma unroll
      for (int n = 0; n < 4; ++n)
#pragma unroll
        for (int j = 0; j < 4; ++j)
          C[(size_t)(row0 + ch * 64 + m * 16 + j) * Ndim + (col0 + n * 16)] =
              acc[ch * 4 + m][n][j] * s;
}

extern "C" void kernel_launch(void* const* d_in, const int* in_sizes, int n_in,
                              void* d_out, int out_size, void* d_ws,
                              size_t ws_size, hipStream_t stream) {
  const float* x = (const float*)d_in[0];
  const int* q = (const int*)d_in[1];
  const float* scale = (const float*)d_in[2];
  float* out = (float*)d_out;

  const size_t xbf_elems = (size_t)Mdim * Kdim;
  const size_t qbf_elems = (size_t)Ndim * Kdim;
  const size_t ws_needed = (xbf_elems + qbf_elems) * sizeof(u16);
  if (ws_size < ws_needed) return;

  u16* xbf = (u16*)d_ws;
  u16* qbf = xbf + xbf_elems;

  cvt_f32_bf16<<<2048, 256, 0, stream>>>(x, xbf, (int)(xbf_elems / 8));
  cvt_i32_bf16<<<2048, 256, 0, stream>>>(q, qbf, (int)(qbf_elems / 8));
  gemm_bt_256<<<NWG, 512, 0, stream>>>(xbf, qbf, out, scale);
}